// Round 9
// baseline (120.312 us; speedup 1.0000x reference)
//
#include <hip/hip_runtime.h>
#include <math.h>

#define SCALE 4.0f
#define H 128
#define E 64
#define TMAX 32

// d_ws layout (bytes):
//   [0      , 131072)  A-frag f16: f16x8 [mt8(8)][q(4)][kb(4)][lane(64)]
//   [131072 , 139264)  Uc: float4 {U0,U1,Cc,0} per gate row r (512 rows)
#define WS_UC_OFF  131072

typedef _Float16 f16x8 __attribute__((ext_vector_type(8)));   // 4 VGPRs
typedef __attribute__((ext_vector_type(4))) float f32x4;

__device__ __forceinline__ bool is_nanf(float x) {
    return (__float_as_uint(x) & 0x7fffffffu) > 0x7f800000u;
}
__device__ __forceinline__ float rcpf(float x) { return __builtin_amdgcn_rcpf(x); }
__device__ __forceinline__ float sigm(float x) { return rcpf(1.0f + __expf(-x)); }
__device__ __forceinline__ float tanhfast(float x) {
    return fmaf(2.0f, rcpf(1.0f + __expf(-2.0f * x)), -1.0f);
}

// ---------------- Pre-swizzle kernel (unchanged layout) ----------------
__global__ __launch_bounds__(256)
void prep_kernel(const float* __restrict__ W_hh,
                 const float* __restrict__ W_ih,
                 const float* __restrict__ W_emb,
                 const float* __restrict__ b_emb,
                 const float* __restrict__ b_ih,
                 const float* __restrict__ b_hh,
                 char* __restrict__ ws)
{
    const int gid = blockIdx.x * 256 + threadIdx.x;
    if (gid < 8192) {
        const int lane = gid & 63;
        const int kb   = (gid >> 6) & 3;
        const int q    = (gid >> 8) & 3;
        const int w8   = gid >> 10;          // M-tile sub-index
        const int mt   = q * 8 + w8;
        const int row  = mt * 16 + (lane & 15);
        const int col0 = kb * 32 + (lane >> 4) * 8;
        const float* p = W_hh + (size_t)row * H + col0;
        f16x8 h8;
        #pragma unroll
        for (int j = 0; j < 8; ++j) h8[j] = (_Float16)p[j];
        *(f16x8*)(ws + (size_t)gid * 16) = h8;
    } else if (gid < 8192 + 512) {
        const int r = gid - 8192;
        const float* wr = W_ih + (size_t)r * E;
        float s0 = 0.f, s1 = 0.f, sc = 0.f;
        #pragma unroll 8
        for (int k = 0; k < E; ++k) {
            const float wv = wr[k];
            s0 += wv * W_emb[2 * k + 0];
            s1 += wv * W_emb[2 * k + 1];
            sc += wv * b_emb[k];
        }
        f32x4 v = {s0, s1, sc + b_ih[r] + b_hh[r], 0.0f};
        *(f32x4*)(ws + WS_UC_OFF + (size_t)r * 16) = v;
    }
}

// ---------------- Main kernel ----------------
// R9: 256-thread blocks (4 waves), ONE scene per block, 512 blocks ->
// TWO independent blocks per CU (R8 had one 8-wave lockstep chain/CU).
// Each wave owns 32 hidden units = 8 M-tiles (2 per gate); per-CU MFMA
// and VALU totals match R8, but the two blocks' barrier/latency chains
// overlap, and barriers span only 4 waves. h is a flat k-indexed f16
// hi/lo array (parity double-buffered): B-reads are 4-address broadcast
// b128 (conflict-free), writebacks 2-way-same-dword u16 (free).
__global__ __launch_bounds__(256, 2)
void lstm_disc_kernel(
    const float* __restrict__ observed,
    const float* __restrict__ prediction,
    const int* __restrict__ batch_split,
    const char* __restrict__ ws,
    const float* __restrict__ W1, const float* __restrict__ b1,
    const float* __restrict__ W2, const float* __restrict__ b2,
    const float* __restrict__ W3, const float* __restrict__ b3,
    float* __restrict__ out,
    int N, int T_obs, int T_total, int n_scenes)
{
    __shared__ __align__(16) _Float16 hbh[2][H];   // h hi, parity dbuf
    __shared__ __align__(16) _Float16 hbl[2][H];   // h lo
    __shared__ float h32[H];
    __shared__ float px[TMAX], py[TMAX];
    __shared__ float aA[TMAX], bA[TMAX];
    __shared__ int   mA[TMAX];
    __shared__ float x1s[H / 2];
    __shared__ float x2s[H / 4];

    const int tid  = threadIdx.x;
    const int wave = tid >> 6;
    const int lane = tid & 63;
    const int ln15 = lane & 15;
    const int g4   = lane >> 4;
    const int ea   = ln15 >> 2;           // C reg index
    const int es   = ln15 & 3;            // replica slot
    const int u0   = wave * 32 + g4 * 4 + ea;   // this lane's units
    const int u1   = u0 + 16;
    const int scene = blockIdx.x;

    // ---- A fragments: 8 tiles (q, i) x 4 kb, coalesced dwordx4 ----
    f16x8 ahi[4][2][4];
    #pragma unroll
    for (int q = 0; q < 4; ++q)
        #pragma unroll
        for (int i = 0; i < 2; ++i)
            #pragma unroll
            for (int kb = 0; kb < 4; ++kb) {
                const size_t slot = ((size_t)(((wave * 2 + i) * 4 + q) * 4 + kb) * 64 + lane) * 16;
                ahi[q][i][kb] = *(const f16x8*)(ws + slot);
            }

    // ---- Folded input terms for units u0, u1 ----
    float U0a[4], U1a[4], Cca[4], U0b[4], U1b[4], Ccb[4];
    #pragma unroll
    for (int q = 0; q < 4; ++q) {
        const f32x4 va = *(const f32x4*)(ws + WS_UC_OFF + (size_t)(u0 + q * H) * 16);
        U0a[q] = va[0]; U1a[q] = va[1]; Cca[q] = va[2];
        const f32x4 vb = *(const f32x4*)(ws + WS_UC_OFF + (size_t)(u1 + q * H) * 16);
        U0b[q] = vb[0]; U1b[q] = vb[1]; Ccb[q] = vb[2];
    }

    // ---- Stage track, zero h buffers ----
    if (tid < TMAX && tid < T_total) {
        const int t = tid;
        const int agent = (scene < n_scenes) ? batch_split[scene] : 0;
        const float* src = (t < T_obs)
            ? (observed   + (size_t)t           * N * 2)
            : (prediction + (size_t)(t - T_obs) * N * 2);
        px[t] = src[(size_t)agent * 2 + 0];
        py[t] = src[(size_t)agent * 2 + 1];
    }
    if (tid < 128) {      // hbh/hbl each 2*128 f16 = 128 dwords
        ((int*)hbh)[tid] = 0;
        ((int*)hbl)[tid] = 0;
    }
    __syncthreads();
    if (tid < T_total - 1) {
        const int t = tid;
        const bool m = !(is_nanf(px[t]) || is_nanf(px[t + 1]));
        aA[t] = m ? SCALE * (px[t + 1] - px[t]) : 0.0f;
        bA[t] = m ? SCALE * (py[t + 1] - py[t]) : 0.0f;
        mA[t] = m ? 1 : 0;
    }

    float c0 = 0.f, h0 = 0.f, c1 = 0.f, h1 = 0.f;
    __syncthreads();

    // ---- Recurrent loop: ONE 4-wave barrier per step ----
    for (int t = 0; t < T_total - 1; ++t) {
        const int rp = t & 1, wp = rp ^ 1;

        const float aa = aA[t];
        const float bb = bA[t];
        const int   mm = mA[t];

        // B fragments: 4 distinct b128 addrs (g4), 16-lane broadcast.
        f16x8 bhi[4], blo[4];
        #pragma unroll
        for (int kb = 0; kb < 4; ++kb) {
            bhi[kb] = *(const f16x8*)&hbh[rp][kb * 32 + g4 * 8];
            blo[kb] = *(const f16x8*)&hbl[rp][kb * 32 + g4 * 8];
        }

        // 8 independent 8-deep chains (tile (q,i); hi then lo).
        f32x4 acc[4][2];
        #pragma unroll
        for (int q = 0; q < 4; ++q) {
            acc[q][0] = (f32x4){0.f, 0.f, 0.f, 0.f};
            acc[q][1] = (f32x4){0.f, 0.f, 0.f, 0.f};
        }
        #pragma unroll
        for (int kb = 0; kb < 4; ++kb)
            #pragma unroll
            for (int q = 0; q < 4; ++q) {
                acc[q][0] = __builtin_amdgcn_mfma_f32_16x16x32_f16(ahi[q][0][kb], bhi[kb], acc[q][0], 0, 0, 0);
                acc[q][1] = __builtin_amdgcn_mfma_f32_16x16x32_f16(ahi[q][1][kb], bhi[kb], acc[q][1], 0, 0, 0);
            }
        #pragma unroll
        for (int kb = 0; kb < 4; ++kb)
            #pragma unroll
            for (int q = 0; q < 4; ++q) {
                acc[q][0] = __builtin_amdgcn_mfma_f32_16x16x32_f16(ahi[q][0][kb], blo[kb], acc[q][0], 0, 0, 0);
                acc[q][1] = __builtin_amdgcn_mfma_f32_16x16x32_f16(ahi[q][1][kb], blo[kb], acc[q][1], 0, 0, 0);
            }

        // Epilogue, unit u0 (reg ea of tile i=0).
        {
            const float p0 = acc[0][0][ea] + Cca[0] + aa * U0a[0] + bb * U1a[0];
            const float p1 = acc[1][0][ea] + Cca[1] + aa * U0a[1] + bb * U1a[1];
            const float p2 = acc[2][0][ea] + Cca[2] + aa * U0a[2] + bb * U1a[2];
            const float p3 = acc[3][0][ea] + Cca[3] + aa * U0a[3] + bb * U1a[3];
            const float ig = sigm(p0), fg = sigm(p1);
            const float gg = tanhfast(p2), og = sigm(p3);
            const float c2 = fg * c0 + ig * gg;
            const float h2 = og * tanhfast(c2);
            if (mm) { c0 = c2; h0 = h2; }
        }
        // Epilogue, unit u1 (reg ea of tile i=1).
        {
            const float p0 = acc[0][1][ea] + Ccb[0] + aa * U0b[0] + bb * U1b[0];
            const float p1 = acc[1][1][ea] + Ccb[1] + aa * U0b[1] + bb * U1b[1];
            const float p2 = acc[2][1][ea] + Ccb[2] + aa * U0b[2] + bb * U1b[2];
            const float p3 = acc[3][1][ea] + Ccb[3] + aa * U0b[3] + bb * U1b[3];
            const float ig = sigm(p0), fg = sigm(p1);
            const float gg = tanhfast(p2), og = sigm(p3);
            const float c2 = fg * c1 + ig * gg;
            const float h2 = og * tanhfast(c2);
            if (mm) { c1 = c2; h1 = h2; }
        }

        if (es == 0) {   // one writer per unit; 2-way same-dword u16 (free)
            const _Float16 h0h = (_Float16)h0;
            const _Float16 h1h = (_Float16)h1;
            hbh[wp][u0] = h0h;
            hbh[wp][u1] = h1h;
            hbl[wp][u0] = (_Float16)(h0 - (float)h0h);
            hbl[wp][u1] = (_Float16)(h1 - (float)h1h);
            if (t == T_total - 2) { h32[u0] = h0; h32[u1] = h1; }
        }
        __syncthreads();
    }

    // ---- MLP head: 128 -> 64 -> 32 -> 1, relu ----
    if (tid < H / 2) {
        const float4* wr = (const float4*)(W1 + (size_t)tid * H);
        const float4* hv = (const float4*)h32;
        float sum = b1[tid];
        #pragma unroll
        for (int k = 0; k < H / 4; ++k) {
            const float4 w = wr[k], h = hv[k];
            sum += h.x * w.x + h.y * w.y + h.z * w.z + h.w * w.w;
        }
        x1s[tid] = fmaxf(sum, 0.f);
    }
    __syncthreads();
    if (tid < H / 4) {
        const float4* wr = (const float4*)(W2 + (size_t)tid * (H / 2));
        const float4* xv = (const float4*)x1s;
        float sum = b2[tid];
        #pragma unroll
        for (int k = 0; k < H / 8; ++k) {
            const float4 w = wr[k], x = xv[k];
            sum += x.x * w.x + x.y * w.y + x.z * w.z + x.w * w.w;
        }
        x2s[tid] = fmaxf(sum, 0.f);
    }
    __syncthreads();
    if (tid == 0 && scene < n_scenes) {
        float sum = b3[0];
        #pragma unroll
        for (int k = 0; k < H / 4; ++k) sum += x2s[k] * W3[k];
        out[scene] = fmaxf(sum, 0.f);
    }
}

extern "C" void kernel_launch(void* const* d_in, const int* in_sizes, int n_in,
                              void* d_out, int out_size, void* d_ws, size_t ws_size,
                              hipStream_t stream) {
    const float* observed   = (const float*)d_in[0];
    const float* prediction = (const float*)d_in[1];
    // d_in[2] = goals (unused by the reference computation)
    const int*   batch_split = (const int*)d_in[3];
    const float* W_emb = (const float*)d_in[4];
    const float* b_emb = (const float*)d_in[5];
    const float* W_ih  = (const float*)d_in[6];
    const float* W_hh  = (const float*)d_in[7];
    const float* b_ih  = (const float*)d_in[8];
    const float* b_hh  = (const float*)d_in[9];
    const float* W1 = (const float*)d_in[10];
    const float* b1 = (const float*)d_in[11];
    const float* W2 = (const float*)d_in[12];
    const float* b2 = (const float*)d_in[13];
    const float* W3 = (const float*)d_in[14];
    const float* b3 = (const float*)d_in[15];
    float* out = (float*)d_out;

    const int N       = in_sizes[2] / 2;               // goals is (N,2)
    const int T_obs   = in_sizes[0] / (2 * N);         // observed (T_obs,N,2)
    const int T_total = T_obs + in_sizes[1] / (2 * N); // 21
    const int n_scenes = in_sizes[3] - 1;              // batch_split has n+1 entries

    prep_kernel<<<34, 256, 0, stream>>>(
        W_hh, W_ih, W_emb, b_emb, b_ih, b_hh, (char*)d_ws);

    lstm_disc_kernel<<<n_scenes, 256, 0, stream>>>(   // 1 scene/block, 2 blocks/CU
        observed, prediction, batch_split, (const char*)d_ws,
        W1, b1, W2, b2, W3, b3,
        out, N, T_obs, T_total, n_scenes);
}

// Round 10
// 103.181 us; speedup vs baseline: 1.1660x; 1.1660x over previous
//
#include <hip/hip_runtime.h>
#include <math.h>

#define SCALE 4.0f
#define H 128
#define E 64
#define NS 2            // scenes per block
#define TMAX 32

// d_ws layout (bytes):
//   [0      , 131072)  A-frag f16: f16x8 [mt8(8)][q(4)][kb(4)][lane(64)]
//   [131072 , 139264)  Uc: float4 {U0,U1,Cc,0} per gate row r (512 rows)
#define WS_UC_OFF  131072

typedef _Float16 f16x8 __attribute__((ext_vector_type(8)));   // 4 VGPRs
typedef __attribute__((ext_vector_type(4))) float f32x4;

__device__ __forceinline__ bool is_nanf(float x) {
    return (__float_as_uint(x) & 0x7fffffffu) > 0x7f800000u;
}
__device__ __forceinline__ float rcpf(float x) { return __builtin_amdgcn_rcpf(x); }
__device__ __forceinline__ float sigm(float x) { return rcpf(1.0f + __expf(-x)); }
__device__ __forceinline__ float tanhfast(float x) {
    return fmaf(2.0f, rcpf(1.0f + __expf(-2.0f * x)), -1.0f);
}
// Swap values with lane^1 (BitMode swizzle, xor_mask=1).
__device__ __forceinline__ float swz_xor1(float v) {
    return __int_as_float(__builtin_amdgcn_ds_swizzle(__float_as_int(v), 0x041F));
}

// ---------------- Pre-swizzle kernel (same layout as R8/R9) ----------------
__global__ __launch_bounds__(256)
void prep_kernel(const float* __restrict__ W_hh,
                 const float* __restrict__ W_ih,
                 const float* __restrict__ W_emb,
                 const float* __restrict__ b_emb,
                 const float* __restrict__ b_ih,
                 const float* __restrict__ b_hh,
                 char* __restrict__ ws)
{
    const int gid = blockIdx.x * 256 + threadIdx.x;
    if (gid < 8192) {
        const int lane = gid & 63;
        const int kb   = (gid >> 6) & 3;
        const int q    = (gid >> 8) & 3;
        const int w8   = gid >> 10;
        const int mt   = q * 8 + w8;
        const int row  = mt * 16 + (lane & 15);
        const int col0 = kb * 32 + (lane >> 4) * 8;
        const float* p = W_hh + (size_t)row * H + col0;
        f16x8 h8;
        #pragma unroll
        for (int j = 0; j < 8; ++j) h8[j] = (_Float16)p[j];
        *(f16x8*)(ws + (size_t)gid * 16) = h8;
    } else if (gid < 8192 + 512) {
        const int r = gid - 8192;
        const float* wr = W_ih + (size_t)r * E;
        float s0 = 0.f, s1 = 0.f, sc = 0.f;
        #pragma unroll 8
        for (int k = 0; k < E; ++k) {
            const float wv = wr[k];
            s0 += wv * W_emb[2 * k + 0];
            s1 += wv * W_emb[2 * k + 1];
            sc += wv * b_emb[k];
        }
        f32x4 v = {s0, s1, sc + b_ih[r] + b_hh[r], 0.0f};
        *(f32x4*)(ws + WS_UC_OFF + (size_t)r * 16) = v;
    }
}

// ---------------- Main kernel ----------------
// R10: hi/lo-in-columns. B column n = 4r + c: scene = c>>1, term = c&1
// (h_hi / h_lo), r = replica. ONE MFMA pass computes both terms into
// different C columns; epilogue combines with a ds_swizzle(xor 1) + add.
// Per wave: 4 M-tiles (all gates of its 16 units) x 4 kb = 16 MFMA/step
// (R8 was 32), A-frags 64 VGPRs (stays out of the R7/R9 AGPR-churn
// regime). NS=2 scenes, 512 threads, 256 blocks = 1/CU. Every lane does
// the epilogue for unit eu / scene esc and writes exactly one f16 of the
// next h (term c&1) -- unmasked, 2-way banked (free). One barrier/step.
__global__ __launch_bounds__(512, 2)
void lstm_disc_kernel(
    const float* __restrict__ observed,
    const float* __restrict__ prediction,
    const int* __restrict__ batch_split,
    const char* __restrict__ ws,
    const float* __restrict__ W1, const float* __restrict__ b1,
    const float* __restrict__ W2, const float* __restrict__ b2,
    const float* __restrict__ W3, const float* __restrict__ b3,
    float* __restrict__ out,
    int N, int T_obs, int T_total, int n_scenes)
{
    // h terms, parity double-buffered: [par][kb][c][k'] (4 KB total).
    __shared__ __align__(16) _Float16 hT[2][4][4][32];
    __shared__ float h32[NS][H];
    __shared__ float px[NS][TMAX], py[NS][TMAX];
    __shared__ float aA[NS][TMAX], bA[NS][TMAX];
    __shared__ int   mA[NS][TMAX];
    __shared__ float x1s[NS][H / 2];
    __shared__ float x2s[NS][H / 4];

    const int tid  = threadIdx.x;
    const int wave = tid >> 6;
    const int lane = tid & 63;
    const int ln15 = lane & 15;
    const int g4   = lane >> 4;
    const int c    = ln15 & 3;        // column slot: scene = c>>1, term = c&1
    const int r    = ln15 >> 2;       // C reg index / unit sub-index
    const int esc  = c >> 1;          // this lane's scene
    const int term = c & 1;           // 0 = hi writer, 1 = lo writer
    const int eu   = wave * 16 + g4 * 4 + r;   // this lane's hidden unit
    const int sc0  = blockIdx.x * NS;

    // ---- A fragments: 4 tiles (q) x 4 kb, coalesced dwordx4 ----
    f16x8 afr[4][4];
    #pragma unroll
    for (int q = 0; q < 4; ++q)
        #pragma unroll
        for (int kb = 0; kb < 4; ++kb) {
            const size_t slot = ((size_t)((wave * 4 + q) * 4 + kb) * 64 + lane) * 16;
            afr[q][kb] = *(const f16x8*)(ws + slot);
        }

    // ---- Folded input terms for unit eu ----
    float U0r[4], U1r[4], Ccr[4];
    #pragma unroll
    for (int q = 0; q < 4; ++q) {
        const f32x4 v = *(const f32x4*)(ws + WS_UC_OFF + (size_t)(eu + q * H) * 16);
        U0r[q] = v[0]; U1r[q] = v[1]; Ccr[q] = v[2];
    }

    // ---- Stage tracks, zero h buffers ----
    if (tid < NS * TMAX) {
        const int s = tid >> 5, t = tid & 31;
        const int scene = sc0 + s;
        const int agent = (scene < n_scenes) ? batch_split[scene] : 0;
        if (t < T_total) {
            const float* src = (t < T_obs)
                ? (observed   + (size_t)t           * N * 2)
                : (prediction + (size_t)(t - T_obs) * N * 2);
            px[s][t] = src[(size_t)agent * 2 + 0];
            py[s][t] = src[(size_t)agent * 2 + 1];
        }
    }
    if (tid < 512) ((int*)hT)[tid] = 0;   // 2*4*4*32 f16 = 512 dwords
    __syncthreads();

    if (tid < NS * TMAX) {
        const int s = tid >> 5, t = tid & 31;
        if (t < T_total - 1) {
            const bool m = !(is_nanf(px[s][t]) || is_nanf(px[s][t + 1]));
            aA[s][t] = m ? SCALE * (px[s][t + 1] - px[s][t]) : 0.0f;
            bA[s][t] = m ? SCALE * (py[s][t + 1] - py[s][t]) : 0.0f;
            mA[s][t] = m ? 1 : 0;
        }
    }

    // Writeback coords: this lane writes term (c&1) of unit eu, scene esc.
    const int wb_kb = eu >> 5;
    const int wb_k  = eu & 31;

    float c_st = 0.f, h_st = 0.f;
    __syncthreads();

    // ---- Recurrent loop: ONE barrier per step ----
    for (int t = 0; t < T_total - 1; ++t) {
        const int rp = t & 1, wp = rp ^ 1;

        const float aa = aA[esc][t];
        const float bb = bA[esc][t];
        const int   mm = mA[esc][t];

        // B fragments: lane (n=ln15, kslice=g4) reads column c's slice.
        // 16 distinct b128 addrs, 2-way banks, 4-lane broadcast: free.
        f16x8 bf[4];
        #pragma unroll
        for (int kb = 0; kb < 4; ++kb)
            bf[kb] = *(const f16x8*)&hT[rp][kb][c][g4 * 8];

        // 4 independent 4-deep chains.
        f32x4 acc[4];
        #pragma unroll
        for (int q = 0; q < 4; ++q) acc[q] = (f32x4){0.f, 0.f, 0.f, 0.f};
        #pragma unroll
        for (int kb = 0; kb < 4; ++kb)
            #pragma unroll
            for (int q = 0; q < 4; ++q)
                acc[q] = __builtin_amdgcn_mfma_f32_16x16x32_f16(afr[q][kb], bf[kb], acc[q], 0, 0, 0);

        // Combine hi+lo partner columns (lane^1), then epilogue.
        float p[4];
        #pragma unroll
        for (int q = 0; q < 4; ++q) {
            const float own = acc[q][r];
            p[q] = own + swz_xor1(own) + Ccr[q] + aa * U0r[q] + bb * U1r[q];
        }
        const float ig = sigm(p[0]);
        const float fg = sigm(p[1]);
        const float gg = tanhfast(p[2]);
        const float og = sigm(p[3]);
        const float c2 = fg * c_st + ig * gg;
        const float h2 = og * tanhfast(c2);
        if (mm) { c_st = c2; h_st = h2; }

        // Every lane writes its term of h[eu] for scene esc.
        const _Float16 hhi = (_Float16)h_st;
        const _Float16 wv  = term ? (_Float16)(h_st - (float)hhi) : hhi;
        hT[wp][wb_kb][c][wb_k] = wv;
        if (t == T_total - 2 && term == 0) h32[esc][eu] = h_st;

        __syncthreads();
    }

    // ---- MLP head: 128 -> 64 -> 32 -> 1, relu (NS=2 scenes) ----
    if (tid < NS * (H / 2)) {
        const int s = tid >> 6, u = tid & 63;
        const float4* wr = (const float4*)(W1 + (size_t)u * H);
        const float4* hv = (const float4*)h32[s];
        float sum = b1[u];
        #pragma unroll
        for (int k = 0; k < H / 4; ++k) {
            const float4 w = wr[k], h = hv[k];
            sum += h.x * w.x + h.y * w.y + h.z * w.z + h.w * w.w;
        }
        x1s[s][u] = fmaxf(sum, 0.f);
    }
    __syncthreads();
    if (tid < NS * (H / 4)) {
        const int s = tid >> 5, u = tid & 31;
        const float4* wr = (const float4*)(W2 + (size_t)u * (H / 2));
        const float4* xv = (const float4*)x1s[s];
        float sum = b2[u];
        #pragma unroll
        for (int k = 0; k < H / 8; ++k) {
            const float4 w = wr[k], x = xv[k];
            sum += x.x * w.x + x.y * w.y + x.z * w.z + x.w * w.w;
        }
        x2s[s][u] = fmaxf(sum, 0.f);
    }
    __syncthreads();
    if (tid < NS) {
        const int scene = sc0 + tid;
        if (scene < n_scenes) {
            float sum = b3[0];
            #pragma unroll
            for (int k = 0; k < H / 4; ++k) sum += x2s[tid][k] * W3[k];
            out[scene] = fmaxf(sum, 0.f);
        }
    }
}

extern "C" void kernel_launch(void* const* d_in, const int* in_sizes, int n_in,
                              void* d_out, int out_size, void* d_ws, size_t ws_size,
                              hipStream_t stream) {
    const float* observed   = (const float*)d_in[0];
    const float* prediction = (const float*)d_in[1];
    // d_in[2] = goals (unused by the reference computation)
    const int*   batch_split = (const int*)d_in[3];
    const float* W_emb = (const float*)d_in[4];
    const float* b_emb = (const float*)d_in[5];
    const float* W_ih  = (const float*)d_in[6];
    const float* W_hh  = (const float*)d_in[7];
    const float* b_ih  = (const float*)d_in[8];
    const float* b_hh  = (const float*)d_in[9];
    const float* W1 = (const float*)d_in[10];
    const float* b1 = (const float*)d_in[11];
    const float* W2 = (const float*)d_in[12];
    const float* b2 = (const float*)d_in[13];
    const float* W3 = (const float*)d_in[14];
    const float* b3 = (const float*)d_in[15];
    float* out = (float*)d_out;

    const int N       = in_sizes[2] / 2;               // goals is (N,2)
    const int T_obs   = in_sizes[0] / (2 * N);         // observed (T_obs,N,2)
    const int T_total = T_obs + in_sizes[1] / (2 * N); // 21
    const int n_scenes = in_sizes[3] - 1;              // batch_split has n+1 entries

    prep_kernel<<<34, 256, 0, stream>>>(
        W_hh, W_ih, W_emb, b_emb, b_ih, b_hh, (char*)d_ws);

    const int nblocks = (n_scenes + NS - 1) / NS;      // 256 blocks, 1/CU
    lstm_disc_kernel<<<nblocks, 512, 0, stream>>>(
        observed, prediction, batch_split, (const char*)d_ws,
        W1, b1, W2, b2, W3, b3,
        out, N, T_obs, T_total, n_scenes);
}